// Round 1
// baseline (754.485 us; speedup 1.0000x reference)
//
#include <hip/hip_runtime.h>
#include <hip/hip_fp16.h>

typedef _Float16 f16;
typedef _Float16 f16x4 __attribute__((ext_vector_type(4)));
typedef _Float16 f16x8 __attribute__((ext_vector_type(8)));
typedef float    f32x4 __attribute__((ext_vector_type(4)));

#define T_STEPS 2048
#define BATCH   16
#define DIM     1024
#define M_TOTAL (T_STEPS * BATCH)  // 32768

// ---------------------------------------------------------------------------
// async global->LDS (16B per lane). LDS dest must be wave-uniform base.
__device__ __forceinline__ void async16(void* lds, const void* g) {
  __builtin_amdgcn_global_load_lds(
      (const __attribute__((address_space(1))) void*)g,
      (__attribute__((address_space(3))) void*)lds, 16, 0, 0);
}

// ---------------------------------------------------------------------------
// f32 -> f16 convert, 8 elems/thread
__global__ void cvt_kernel(const float* __restrict__ src, f16* __restrict__ dst,
                           int n8) {
  int i = blockIdx.x * 256 + threadIdx.x;
  if (i >= n8) return;
  const float4* s4 = reinterpret_cast<const float4*>(src);
  float4 a = s4[2 * i], b = s4[2 * i + 1];
  f16x8 o;
  o[0] = (f16)a.x; o[1] = (f16)a.y; o[2] = (f16)a.z; o[3] = (f16)a.w;
  o[4] = (f16)b.x; o[5] = (f16)b.y; o[6] = (f16)b.z; o[7] = (f16)b.w;
  *reinterpret_cast<f16x8*>(dst + (size_t)i * 8) = o;
}

// ---------------------------------------------------------------------------
// Dual GEMM: C1[m,e] = sum_d x[m,d]*W[e,d] ; C2 likewise vs W_g.
// Epilogue writes P[m,e] = (C1 + b[e]) * sigmoid(C2 + bg[e]) as f16.
// 128x128 tile per matrix, BK=32, 4 waves (2x2 of 64x64), 16x16x32 f16 MFMA.
__global__ __launch_bounds__(256, 2)
void dual_gemm(const f16* __restrict__ xh, const f16* __restrict__ wh,
               const f16* __restrict__ wgh, const float* __restrict__ bias,
               const float* __restrict__ biasg, f16* __restrict__ P) {
  __shared__ f16 As[128 * 32];
  __shared__ f16 Bs[128 * 32];
  __shared__ f16 Gs[128 * 32];

  const int tid = threadIdx.x;
  const int bid = blockIdx.x;
  // XCD-aware swizzle (nwg = 2048, divisible by 8): each XCD gets a
  // contiguous 256-block chunk = 32 row-bands x 8 col-blocks (B L2-resident).
  const int swz = ((bid & 7) << 8) | (bid >> 3);
  const int m0 = (swz >> 3) * 128;
  const int e0 = (swz & 7) * 128;

  const int lane = tid & 63;
  const int wave = tid >> 6;
  const int wrow = (wave >> 1) * 64;
  const int wcol = (wave & 1) * 64;
  const int fr = lane & 15;   // fragment row/col within 16
  const int fc = lane >> 4;   // k-chunk (8 f16 each)

  f32x4 acc1[4][4], acc2[4][4];
#pragma unroll
  for (int i = 0; i < 4; ++i)
#pragma unroll
    for (int j = 0; j < 4; ++j) {
      acc1[i][j] = {0.f, 0.f, 0.f, 0.f};
      acc2[i][j] = {0.f, 0.f, 0.f, 0.f};
    }

  // staging: 256 threads * 16B = 4KB/call; 2 calls per 128x32 f16 tile (8KB)
  const int    srow  = tid >> 2;                 // 0..63
  const size_t sbyte = (size_t)(tid & 3) * 16;   // 0..48
  const char* ga = (const char*)xh  + ((size_t)(m0 + srow)) * 2048 + sbyte;
  const char* gb = (const char*)wh  + ((size_t)(e0 + srow)) * 2048 + sbyte;
  const char* gg = (const char*)wgh + ((size_t)(e0 + srow)) * 2048 + sbyte;
  char* la = (char*)&As[0] + (size_t)wave * 1024;  // wave-uniform LDS base
  char* lb = (char*)&Bs[0] + (size_t)wave * 1024;
  char* lg = (char*)&Gs[0] + (size_t)wave * 1024;

  for (int kk = 0; kk < 1024; kk += 32) {
    const size_t ko = (size_t)kk * 2;  // bytes along K
    async16(la,        ga + ko);
    async16(la + 4096, ga + ko + (size_t)64 * 2048);
    async16(lb,        gb + ko);
    async16(lb + 4096, gb + ko + (size_t)64 * 2048);
    async16(lg,        gg + ko);
    async16(lg + 4096, gg + ko + (size_t)64 * 2048);
    asm volatile("s_waitcnt vmcnt(0)" ::: "memory");
    __syncthreads();

    f16x8 af[4], bf[4], gf[4];
#pragma unroll
    for (int i = 0; i < 4; ++i) {
      af[i] = *reinterpret_cast<const f16x8*>(&As[(wrow + i * 16 + fr) * 32 + fc * 8]);
      bf[i] = *reinterpret_cast<const f16x8*>(&Bs[(wcol + i * 16 + fr) * 32 + fc * 8]);
      gf[i] = *reinterpret_cast<const f16x8*>(&Gs[(wcol + i * 16 + fr) * 32 + fc * 8]);
    }
#pragma unroll
    for (int mi = 0; mi < 4; ++mi)
#pragma unroll
      for (int ni = 0; ni < 4; ++ni) {
        acc1[mi][ni] = __builtin_amdgcn_mfma_f32_16x16x32_f16(af[mi], bf[ni], acc1[mi][ni], 0, 0, 0);
        acc2[mi][ni] = __builtin_amdgcn_mfma_f32_16x16x32_f16(af[mi], gf[ni], acc2[mi][ni], 0, 0, 0);
      }
    __syncthreads();
  }

  // epilogue: P = (z1 + b) * sigmoid(z2 + bg), f16 store
#pragma unroll
  for (int ni = 0; ni < 4; ++ni) {
    const int e = e0 + wcol + ni * 16 + fr;
    const float bb  = bias[e];
    const float bbg = biasg[e];
#pragma unroll
    for (int mi = 0; mi < 4; ++mi) {
      const int mrow = m0 + wrow + mi * 16 + fc * 4;
#pragma unroll
      for (int j = 0; j < 4; ++j) {
        float z1 = acc1[mi][ni][j] + bb;
        float z2 = acc2[mi][ni][j] + bbg;
        float s  = 1.0f / (1.0f + __expf(-z2));
        P[(size_t)(mrow + j) * DIM + e] = (f16)(z1 * s);
      }
    }
  }
}

// ---------------------------------------------------------------------------
// DPP-based wave64 sum: after shr 1/2/4/8 + bcast15 + bcast31, lane 63 = total
template <int CTRL>
__device__ __forceinline__ float dpp_add(float x) {
  int m = __builtin_amdgcn_update_dpp(0, __float_as_int(x), CTRL, 0xf, 0xf, true);
  return x + __int_as_float(m);
}

// Sequential scan: one wave per batch row. h kept in 16 f32 regs/lane.
// Layout: element d = c*256 + lane*4 + j  (c=0..3 chunks, j=0..3)
__global__ __launch_bounds__(64)
void scan_kernel(const f16* __restrict__ P, const float* __restrict__ h0,
                 float* __restrict__ hout) {
  const int b = blockIdx.x;
  const int lane = threadIdx.x;

  float h[16];
  {
    const float4* s = reinterpret_cast<const float4*>(h0 + b * DIM);
    float4* d = reinterpret_cast<float4*>(hout + b * DIM);  // h[0] = h0
#pragma unroll
    for (int c = 0; c < 4; ++c) {
      float4 v = s[c * 64 + lane];
      h[c * 4 + 0] = v.x; h[c * 4 + 1] = v.y;
      h[c * 4 + 2] = v.z; h[c * 4 + 3] = v.w;
      d[c * 64 + lane] = v;
    }
  }

  // depth-4 register prefetch of P rows (f16, 16 elems/lane = 4x 8B loads)
  f16x4 pf[4][4];
#pragma unroll
  for (int u = 0; u < 4; ++u) {
    const f16x4* pr = reinterpret_cast<const f16x4*>(P + ((size_t)u * BATCH + b) * DIM);
#pragma unroll
    for (int c = 0; c < 4; ++c) pf[u][c] = pr[c * 64 + lane];
  }

  for (int t0 = 0; t0 < T_STEPS; t0 += 4) {
#pragma unroll
    for (int u = 0; u < 4; ++u) {
      const int t = t0 + u;
      float p[16];
#pragma unroll
      for (int c = 0; c < 4; ++c)
#pragma unroll
        for (int j = 0; j < 4; ++j) p[c * 4 + j] = (float)pf[u][c][j];

      if (t + 4 < T_STEPS) {  // reissue prefetch into slot u
        const f16x4* pr =
            reinterpret_cast<const f16x4*>(P + ((size_t)(t + 4) * BATCH + b) * DIM);
#pragma unroll
        for (int c = 0; c < 4; ++c) pf[u][c] = pr[c * 64 + lane];
      }

      float v[16];
#pragma unroll
      for (int i = 0; i < 16; ++i) v[i] = h[i] + p[i];

      float s0 = 0.f, s1 = 0.f, s2 = 0.f, s3 = 0.f;
#pragma unroll
      for (int j = 0; j < 4; ++j) {
        s0 = fmaf(v[j],      v[j],      s0);
        s1 = fmaf(v[4 + j],  v[4 + j],  s1);
        s2 = fmaf(v[8 + j],  v[8 + j],  s2);
        s3 = fmaf(v[12 + j], v[12 + j], s3);
      }
      float ss = (s0 + s1) + (s2 + s3);
      ss = dpp_add<0x111>(ss);  // row_shr:1
      ss = dpp_add<0x112>(ss);  // row_shr:2
      ss = dpp_add<0x114>(ss);  // row_shr:4
      ss = dpp_add<0x118>(ss);  // row_shr:8
      ss = dpp_add<0x142>(ss);  // row_bcast:15
      ss = dpp_add<0x143>(ss);  // row_bcast:31
      float tot = __int_as_float(__builtin_amdgcn_readlane(__float_as_int(ss), 63));
      float r = rsqrtf(tot * (1.0f / DIM) + 1e-6f);

#pragma unroll
      for (int i = 0; i < 16; ++i) h[i] = v[i] * r;

      float4* hr = reinterpret_cast<float4*>(hout + ((size_t)(t + 1) * BATCH + b) * DIM);
#pragma unroll
      for (int c = 0; c < 4; ++c)
        hr[c * 64 + lane] =
            make_float4(h[c * 4], h[c * 4 + 1], h[c * 4 + 2], h[c * 4 + 3]);
    }
  }
}

// ---------------------------------------------------------------------------
// out = h * silu(h) = h^2 * sigmoid(h), elementwise over hs (h rows 1..T)
__global__ void silu_out_kernel(const float* __restrict__ hsrc,
                                float* __restrict__ out, int n4) {
  int stride = gridDim.x * blockDim.x;
  for (int i = blockIdx.x * blockDim.x + threadIdx.x; i < n4; i += stride) {
    float4 v = reinterpret_cast<const float4*>(hsrc)[i];
    float4 o;
    o.x = v.x * v.x / (1.0f + __expf(-v.x));
    o.y = v.y * v.y / (1.0f + __expf(-v.y));
    o.z = v.z * v.z / (1.0f + __expf(-v.z));
    o.w = v.w * v.w / (1.0f + __expf(-v.w));
    reinterpret_cast<float4*>(out)[i] = o;
  }
}

// ---------------------------------------------------------------------------
extern "C" void kernel_launch(void* const* d_in, const int* in_sizes, int n_in,
                              void* d_out, int out_size, void* d_ws, size_t ws_size,
                              hipStream_t stream) {
  const float* x  = (const float*)d_in[0];  // [T,B,D]
  const float* h0 = (const float*)d_in[1];  // [B,D]
  const float* W  = (const float*)d_in[2];  // [D,D]
  const float* Wg = (const float*)d_in[3];  // [D,D]
  const float* bb = (const float*)d_in[4];  // [D]
  const float* bg = (const float*)d_in[5];  // [D]

  float* out  = (float*)d_out;                              // [T,B,D]
  float* hout = out + (size_t)T_STEPS * BATCH * DIM;        // [T+1,B,D]

  char* ws = (char*)d_ws;
  f16* xh  = (f16*)(ws);                                    // 64 MiB
  f16* wh  = (f16*)(ws + (size_t)67108864);                 // 2 MiB
  f16* wgh = (f16*)(ws + (size_t)69206016);                 // 2 MiB
  f16* P   = (f16*)(ws + (size_t)71303168);                 // 64 MiB

  cvt_kernel<<<16384, 256, 0, stream>>>(x,  xh,  4194304);
  cvt_kernel<<<512,   256, 0, stream>>>(W,  wh,  131072);
  cvt_kernel<<<512,   256, 0, stream>>>(Wg, wgh, 131072);

  dual_gemm<<<2048, 256, 0, stream>>>(xh, wh, wgh, bb, bg, P);

  scan_kernel<<<BATCH, 64, 0, stream>>>(P, h0, hout);

  silu_out_kernel<<<2048, 256, 0, stream>>>(hout + BATCH * DIM, out, 8388608);
}

// Round 2
// 690.157 us; speedup vs baseline: 1.0932x; 1.0932x over previous
//
#include <hip/hip_runtime.h>
#include <hip/hip_fp16.h>

typedef _Float16 f16;
typedef _Float16 f16x4 __attribute__((ext_vector_type(4)));
typedef _Float16 f16x8 __attribute__((ext_vector_type(8)));
typedef float    f32x4 __attribute__((ext_vector_type(4)));

#define T_STEPS 2048
#define BATCH   16
#define DIM     1024
#define M_TOTAL (T_STEPS * BATCH)  // 32768

// ---------------------------------------------------------------------------
// async global->LDS (16B per lane). LDS dest must be wave-uniform base.
__device__ __forceinline__ void async16(void* lds, const void* g) {
  __builtin_amdgcn_global_load_lds(
      (const __attribute__((address_space(1))) void*)g,
      (__attribute__((address_space(3))) void*)lds, 16, 0, 0);
}

// ---------------------------------------------------------------------------
// f32 -> f16 convert, 8 elems/thread
__global__ void cvt_kernel(const float* __restrict__ src, f16* __restrict__ dst,
                           int n8) {
  int i = blockIdx.x * 256 + threadIdx.x;
  if (i >= n8) return;
  const float4* s4 = reinterpret_cast<const float4*>(src);
  float4 a = s4[2 * i], b = s4[2 * i + 1];
  f16x8 o;
  o[0] = (f16)a.x; o[1] = (f16)a.y; o[2] = (f16)a.z; o[3] = (f16)a.w;
  o[4] = (f16)b.x; o[5] = (f16)b.y; o[6] = (f16)b.z; o[7] = (f16)b.w;
  *reinterpret_cast<f16x8*>(dst + (size_t)i * 8) = o;
}

// ---------------------------------------------------------------------------
// Dual GEMM: C1[m,e] = sum_d x[m,d]*W[e,d] ; C2 likewise vs W_g.
// Epilogue writes P[m,e] = (C1 + b[e]) * sigmoid(C2 + bg[e]) as f16.
// 128x128 tile per matrix, BK=32, 4 waves (2x2 of 64x64), 16x16x32 f16 MFMA.
__global__ __launch_bounds__(256, 2)
void dual_gemm(const f16* __restrict__ xh, const f16* __restrict__ wh,
               const f16* __restrict__ wgh, const float* __restrict__ bias,
               const float* __restrict__ biasg, f16* __restrict__ P) {
  __shared__ f16 As[128 * 32];
  __shared__ f16 Bs[128 * 32];
  __shared__ f16 Gs[128 * 32];

  const int tid = threadIdx.x;
  const int bid = blockIdx.x;
  // XCD-aware swizzle (nwg = 2048, divisible by 8): each XCD gets a
  // contiguous 256-block chunk = 32 row-bands x 8 col-blocks (B L2-resident).
  const int swz = ((bid & 7) << 8) | (bid >> 3);
  const int m0 = (swz >> 3) * 128;
  const int e0 = (swz & 7) * 128;

  const int lane = tid & 63;
  const int wave = tid >> 6;
  const int wrow = (wave >> 1) * 64;
  const int wcol = (wave & 1) * 64;
  const int fr = lane & 15;   // fragment row/col within 16
  const int fc = lane >> 4;   // k-chunk (8 f16 each)

  f32x4 acc1[4][4], acc2[4][4];
#pragma unroll
  for (int i = 0; i < 4; ++i)
#pragma unroll
    for (int j = 0; j < 4; ++j) {
      acc1[i][j] = {0.f, 0.f, 0.f, 0.f};
      acc2[i][j] = {0.f, 0.f, 0.f, 0.f};
    }

  // staging: 256 threads * 16B = 4KB/call; 2 calls per 128x32 f16 tile (8KB)
  const int    srow  = tid >> 2;                 // 0..63
  const size_t sbyte = (size_t)(tid & 3) * 16;   // 0..48
  const char* ga = (const char*)xh  + ((size_t)(m0 + srow)) * 2048 + sbyte;
  const char* gb = (const char*)wh  + ((size_t)(e0 + srow)) * 2048 + sbyte;
  const char* gg = (const char*)wgh + ((size_t)(e0 + srow)) * 2048 + sbyte;
  char* la = (char*)&As[0] + (size_t)wave * 1024;  // wave-uniform LDS base
  char* lb = (char*)&Bs[0] + (size_t)wave * 1024;
  char* lg = (char*)&Gs[0] + (size_t)wave * 1024;

  for (int kk = 0; kk < 1024; kk += 32) {
    const size_t ko = (size_t)kk * 2;  // bytes along K
    async16(la,        ga + ko);
    async16(la + 4096, ga + ko + (size_t)64 * 2048);
    async16(lb,        gb + ko);
    async16(lb + 4096, gb + ko + (size_t)64 * 2048);
    async16(lg,        gg + ko);
    async16(lg + 4096, gg + ko + (size_t)64 * 2048);
    asm volatile("s_waitcnt vmcnt(0)" ::: "memory");
    __syncthreads();

    f16x8 af[4], bf[4], gf[4];
#pragma unroll
    for (int i = 0; i < 4; ++i) {
      af[i] = *reinterpret_cast<const f16x8*>(&As[(wrow + i * 16 + fr) * 32 + fc * 8]);
      bf[i] = *reinterpret_cast<const f16x8*>(&Bs[(wcol + i * 16 + fr) * 32 + fc * 8]);
      gf[i] = *reinterpret_cast<const f16x8*>(&Gs[(wcol + i * 16 + fr) * 32 + fc * 8]);
    }
#pragma unroll
    for (int mi = 0; mi < 4; ++mi)
#pragma unroll
      for (int ni = 0; ni < 4; ++ni) {
        acc1[mi][ni] = __builtin_amdgcn_mfma_f32_16x16x32_f16(af[mi], bf[ni], acc1[mi][ni], 0, 0, 0);
        acc2[mi][ni] = __builtin_amdgcn_mfma_f32_16x16x32_f16(af[mi], gf[ni], acc2[mi][ni], 0, 0, 0);
      }
    __syncthreads();
  }

  // epilogue: P = (z1 + b) * sigmoid(z2 + bg), f16 store
#pragma unroll
  for (int ni = 0; ni < 4; ++ni) {
    const int e = e0 + wcol + ni * 16 + fr;
    const float bb  = bias[e];
    const float bbg = biasg[e];
#pragma unroll
    for (int mi = 0; mi < 4; ++mi) {
      const int mrow = m0 + wrow + mi * 16 + fc * 4;
#pragma unroll
      for (int j = 0; j < 4; ++j) {
        float z1 = acc1[mi][ni][j] + bb;
        float z2 = acc2[mi][ni][j] + bbg;
        float s  = 1.0f / (1.0f + __expf(-z2));
        P[(size_t)(mrow + j) * DIM + e] = (f16)(z1 * s);
      }
    }
  }
}

// ---------------------------------------------------------------------------
// DPP-based wave64 sum: after shr 1/2/4/8 + bcast15/31, lane 63 = total
template <int CTRL>
__device__ __forceinline__ float dpp_add(float x) {
  int m = __builtin_amdgcn_update_dpp(0, __float_as_int(x), CTRL, 0xf, 0xf, true);
  return x + __int_as_float(m);
}

// Sequential scan: one wave per batch row. h kept in 16 f32 regs/lane.
// Layout: element d = c*256 + lane*4 + j  (c=0..3 chunks, j=0..3)
// Branch-free depth-8 rolling register prefetch of P rows.
__global__ __launch_bounds__(64)
void scan_kernel(const f16* __restrict__ P, const float* __restrict__ h0,
                 float* __restrict__ hout) {
  const int b = blockIdx.x;
  const int lane = threadIdx.x;

  float h[16];
  {
    const float4* s = reinterpret_cast<const float4*>(h0 + b * DIM);
    float4* d = reinterpret_cast<float4*>(hout + b * DIM);  // h[0] = h0
#pragma unroll
    for (int c = 0; c < 4; ++c) {
      float4 v = s[c * 64 + lane];
      h[c * 4 + 0] = v.x; h[c * 4 + 1] = v.y;
      h[c * 4 + 2] = v.z; h[c * 4 + 3] = v.w;
      d[c * 64 + lane] = v;
    }
  }

  // depth-8 register prefetch of P rows (f16, 16 elems/lane = 4x 8B loads)
  f16x4 pf[8][4];
#pragma unroll
  for (int u = 0; u < 8; ++u) {
    const f16x4* pr = reinterpret_cast<const f16x4*>(P + ((size_t)u * BATCH + b) * DIM);
#pragma unroll
    for (int c = 0; c < 4; ++c) pf[u][c] = pr[c * 64 + lane];
  }

  for (int t0 = 0; t0 < T_STEPS; t0 += 8) {
#pragma unroll
    for (int u = 0; u < 8; ++u) {
      const int t = t0 + u;

      // consume slot u: v = h + (float)p  (fma_mix-friendly form)
      float v[16];
#pragma unroll
      for (int c = 0; c < 4; ++c)
#pragma unroll
        for (int j = 0; j < 4; ++j)
          v[c * 4 + j] = fmaf((float)pf[u][c][j], 1.0f, h[c * 4 + j]);

      // reissue prefetch into slot u, branch-free: wrap index keeps the
      // address valid; wrapped rows are loaded but never consumed.
      {
        const int tp = (t + 8) & (T_STEPS - 1);
        const f16x4* pr =
            reinterpret_cast<const f16x4*>(P + ((size_t)tp * BATCH + b) * DIM);
#pragma unroll
        for (int c = 0; c < 4; ++c) pf[u][c] = pr[c * 64 + lane];
      }

      float s0 = 0.f, s1 = 0.f, s2 = 0.f, s3 = 0.f;
#pragma unroll
      for (int j = 0; j < 4; ++j) {
        s0 = fmaf(v[j],      v[j],      s0);
        s1 = fmaf(v[4 + j],  v[4 + j],  s1);
        s2 = fmaf(v[8 + j],  v[8 + j],  s2);
        s3 = fmaf(v[12 + j], v[12 + j], s3);
      }
      float ss = (s0 + s1) + (s2 + s3);
      ss = dpp_add<0x111>(ss);  // row_shr:1
      ss = dpp_add<0x112>(ss);  // row_shr:2
      ss = dpp_add<0x114>(ss);  // row_shr:4
      ss = dpp_add<0x118>(ss);  // row_shr:8
      ss = dpp_add<0x142>(ss);  // row_bcast:15
      ss = dpp_add<0x143>(ss);  // row_bcast:31
      float tot = __int_as_float(__builtin_amdgcn_readlane(__float_as_int(ss), 63));
      float r = rsqrtf(fmaf(tot, 1.0f / DIM, 1e-6f));

#pragma unroll
      for (int i = 0; i < 16; ++i) h[i] = v[i] * r;

      float4* hr = reinterpret_cast<float4*>(hout + ((size_t)(t + 1) * BATCH + b) * DIM);
#pragma unroll
      for (int c = 0; c < 4; ++c)
        hr[c * 64 + lane] =
            make_float4(h[c * 4], h[c * 4 + 1], h[c * 4 + 2], h[c * 4 + 3]);
    }
  }
}

// ---------------------------------------------------------------------------
// out = h * silu(h) = h^2 * sigmoid(h), elementwise over hs (h rows 1..T)
__global__ void silu_out_kernel(const float* __restrict__ hsrc,
                                float* __restrict__ out, int n4) {
  int stride = gridDim.x * blockDim.x;
  for (int i = blockIdx.x * blockDim.x + threadIdx.x; i < n4; i += stride) {
    float4 v = reinterpret_cast<const float4*>(hsrc)[i];
    float4 o;
    o.x = v.x * v.x / (1.0f + __expf(-v.x));
    o.y = v.y * v.y / (1.0f + __expf(-v.y));
    o.z = v.z * v.z / (1.0f + __expf(-v.z));
    o.w = v.w * v.w / (1.0f + __expf(-v.w));
    reinterpret_cast<float4*>(out)[i] = o;
  }
}

// ---------------------------------------------------------------------------
extern "C" void kernel_launch(void* const* d_in, const int* in_sizes, int n_in,
                              void* d_out, int out_size, void* d_ws, size_t ws_size,
                              hipStream_t stream) {
  const float* x  = (const float*)d_in[0];  // [T,B,D]
  const float* h0 = (const float*)d_in[1];  // [B,D]
  const float* W  = (const float*)d_in[2];  // [D,D]
  const float* Wg = (const float*)d_in[3];  // [D,D]
  const float* bb = (const float*)d_in[4];  // [D]
  const float* bg = (const float*)d_in[5];  // [D]

  float* out  = (float*)d_out;                              // [T,B,D]
  float* hout = out + (size_t)T_STEPS * BATCH * DIM;        // [T+1,B,D]

  char* ws = (char*)d_ws;
  f16* xh  = (f16*)(ws);                                    // 64 MiB
  f16* wh  = (f16*)(ws + (size_t)67108864);                 // 2 MiB
  f16* wgh = (f16*)(ws + (size_t)69206016);                 // 2 MiB
  f16* P   = (f16*)(ws + (size_t)71303168);                 // 64 MiB

  cvt_kernel<<<16384, 256, 0, stream>>>(x,  xh,  4194304);
  cvt_kernel<<<512,   256, 0, stream>>>(W,  wh,  131072);
  cvt_kernel<<<512,   256, 0, stream>>>(Wg, wgh, 131072);

  dual_gemm<<<2048, 256, 0, stream>>>(xh, wh, wgh, bb, bg, P);

  scan_kernel<<<BATCH, 64, 0, stream>>>(P, h0, hout);

  silu_out_kernel<<<2048, 256, 0, stream>>>(hout + BATCH * DIM, out, 8388608);
}